// Round 1
// baseline (1137.474 us; speedup 1.0000x reference)
//
#include <hip/hip_runtime.h>
#include <math.h>

#define HEADS 4
#define DH 64
#define CH 256
#define HW 4096
#define HH 64
#define WW 64
#define BB 2
#define KS 7

// Projection: out[b][pixel][o] = scale * sum_c in[b][c][pixel] * Wm[o][c]
// grid (HW/64, BB, 3): z selects which projection. Block 256 threads.
// Per block: 64 pixels x all 256 outputs, K chunked by 32 with LDS staging.
__global__ __launch_bounds__(256) void proj3_kernel(
    const float* __restrict__ qmap, const float* __restrict__ kvmap1,
    const float* __restrict__ kvmap2, const float* __restrict__ Wq,
    const float* __restrict__ Wkv, float* __restrict__ Qt,
    float* __restrict__ KV1, float* __restrict__ KV2) {
  const float* in; const float* Wm; float* out; float scale;
  switch (blockIdx.z) {
    case 0:  in = qmap;   Wm = Wq;  out = Qt;  scale = 0.125f; break; // 1/sqrt(64)
    case 1:  in = kvmap1; Wm = Wkv; out = KV1; scale = 1.0f;   break;
    default: in = kvmap2; Wm = Wkv; out = KV2; scale = 1.0f;   break;
  }
  __shared__ float lin[32][64];    // [c_chunk][pixel]
  __shared__ float wl[256][33];    // [o][c_chunk], +1 pad: bank = (o+cc)%32, conflict-free
  const int b = blockIdx.y, t = threadIdx.x;
  const int p0 = blockIdx.x * 64;
  const float* inb = in + (size_t)b * CH * HW + p0;
  float acc[64];
  #pragma unroll
  for (int i = 0; i < 64; ++i) acc[i] = 0.f;

  for (int c0 = 0; c0 < CH; c0 += 32) {
    __syncthreads();  // protect LDS from previous iteration's readers
    #pragma unroll
    for (int r = 0; r < 8; ++r) {           // 32x64 input tile, coalesced 256B rows
      int idx = r * 256 + t;
      lin[idx >> 6][idx & 63] = inb[(size_t)(c0 + (idx >> 6)) * HW + (idx & 63)];
    }
    #pragma unroll
    for (int r = 0; r < 32; ++r) {          // 256x32 weight tile
      int idx = r * 256 + t;
      wl[idx >> 5][idx & 31] = Wm[(size_t)(idx >> 5) * CH + c0 + (idx & 31)];
    }
    __syncthreads();
    // thread t owns output channel o = t for all 64 pixels
    for (int cc = 0; cc < 32; ++cc) {
      float wv = wl[t][cc];
      const float4* lp = (const float4*)(&lin[cc][0]);  // broadcast reads
      #pragma unroll
      for (int k4 = 0; k4 < 16; ++k4) {
        float4 v = lp[k4];
        acc[k4 * 4 + 0] = fmaf(wv, v.x, acc[k4 * 4 + 0]);
        acc[k4 * 4 + 1] = fmaf(wv, v.y, acc[k4 * 4 + 1]);
        acc[k4 * 4 + 2] = fmaf(wv, v.z, acc[k4 * 4 + 2]);
        acc[k4 * 4 + 3] = fmaf(wv, v.w, acc[k4 * 4 + 3]);
      }
    }
  }
  // out[b][p0+p][o=t]: for fixed p, lanes write consecutive o -> coalesced
  float* ob = out + ((size_t)b * HW + p0) * CH + t;
  #pragma unroll
  for (int p = 0; p < 64; ++p) ob[(size_t)p * CH] = acc[p] * scale;
}

// One 7x7-neighborhood attention branch for one (b, n, pixel), one wave.
// lane = d. kvp = KV base for this (b, n). Returns o_d (pre-average).
// OOB neighbors are zero vectors -> logit exactly 0, included in softmax
// (matches reference's zero-padding, which does NOT mask pad positions).
__device__ __forceinline__ float attn_branch(const float* __restrict__ kvp,
                                             float q, int lane, int y, int xc) {
  float kreg[49], lg[49];
  #pragma unroll
  for (int i = 0; i < KS; ++i) {
    int yy = y + i - 3;
    #pragma unroll
    for (int j = 0; j < KS; ++j) {
      int xx = xc + j - 3;
      int p = i * KS + j;
      float kv = 0.f;
      if (yy >= 0 && yy < HH && xx >= 0 && xx < WW)
        kv = kvp[(size_t)(yy * WW + xx) * CH + lane];   // 256B coalesced
      kreg[p] = kv;
      float prod = q * kv;
      #pragma unroll
      for (int s = 1; s < 64; s <<= 1) prod += __shfl_xor(prod, s, 64);
      lg[p] = prod;                                      // all lanes hold logit
    }
  }
  float m = lg[0];
  #pragma unroll
  for (int p = 1; p < 49; ++p) m = fmaxf(m, lg[p]);
  float den = 0.f, o = 0.f;
  #pragma unroll
  for (int p = 0; p < 49; ++p) {
    float e = __expf(lg[p] - m);
    den += e;
    o = fmaf(e, kreg[p], o);
  }
  return o / den;
}

// grid (HW/4, BB*HEADS), block 256 = 4 waves; wave w -> pixel blockIdx.x*4+w
__global__ __launch_bounds__(256) void attn_kernel(
    const float* __restrict__ Qt, const float* __restrict__ KV1,
    const float* __restrict__ KV2, float* __restrict__ out) {
  const int t = threadIdx.x;
  const int lane = t & 63, wv = t >> 6;
  const int x = blockIdx.x * 4 + wv;
  const int bn = blockIdx.y, b = bn >> 2, n = bn & 3;
  const int y = x >> 6, xc = x & 63;
  const float q = Qt[((size_t)b * HW + x) * CH + n * DH + lane];
  const size_t base = (size_t)b * HW * CH + (size_t)n * DH;
  float o = attn_branch(KV1 + base, q, lane, y, xc)
          + attn_branch(KV2 + base, q, lane, y, xc);
  out[(((size_t)b * HEADS + n) * DH + lane) * HW + x] = 0.5f * o;
}

extern "C" void kernel_launch(void* const* d_in, const int* in_sizes, int n_in,
                              void* d_out, int out_size, void* d_ws, size_t ws_size,
                              hipStream_t stream) {
  const float* kvmap1 = (const float*)d_in[0];
  const float* qmap   = (const float*)d_in[1];
  const float* kvmap2 = (const float*)d_in[2];
  const float* Wq     = (const float*)d_in[3];
  const float* Wkv    = (const float*)d_in[4];
  float* out = (float*)d_out;

  // workspace carve: Qt | KV1 | KV2, each B*HW*CH f32 = 8 MB (24 MB total)
  float* Qt  = (float*)d_ws;
  float* KV1 = Qt  + (size_t)BB * HW * CH;
  float* KV2 = KV1 + (size_t)BB * HW * CH;

  dim3 pgrid(HW / 64, BB, 3);
  proj3_kernel<<<pgrid, 256, 0, stream>>>(qmap, kvmap1, kvmap2, Wq, Wkv, Qt, KV1, KV2);

  dim3 agrid(HW / 4, BB * HEADS);
  attn_kernel<<<agrid, 256, 0, stream>>>(Qt, KV1, KV2, out);
}

// Round 2
// 206.401 us; speedup vs baseline: 5.5110x; 5.5110x over previous
//
#include <hip/hip_runtime.h>
#include <math.h>

#define HEADS 4
#define DH 64
#define CH 256
#define HW 4096
#define HH 64
#define WW 64
#define BB 2
#define KS 7

#define NPOS 224        // union rows: 14 uy x 16 ux (ux 14,15 are pad, always masked)
#define ROWB 448        // bytes per LDS row (224 bf16)

typedef __attribute__((ext_vector_type(8))) short bf16x8;
typedef __attribute__((ext_vector_type(4))) float f32x4;
typedef __attribute__((ext_vector_type(4))) short short4_t;

__device__ __forceinline__ short f2bf(float x) {
  union { float f; unsigned u; } v; v.f = x;
  unsigned r = (v.u + 0x7fffu + ((v.u >> 16) & 1u)) >> 16;  // RNE
  return (short)r;
}

// XOR swizzle on byte address: spreads 8 consecutive rows (stride 448B) over
// distinct 16B slots -> <=2-way LDS bank conflict on b128 reads. Same formula
// on write and read sides (both-sides-or-neither).
__device__ __forceinline__ int swz(int row, int byte_off) {
  return byte_off ^ ((row & 7) << 4);
}

// ---------------- projection: out[b][pix][o] = scale * sum_c in[b][c][pix] W[o][c]
// (unchanged f32 compute; now stores bf16 for the MFMA attention consumer)
__global__ __launch_bounds__(256) void proj3_kernel(
    const float* __restrict__ qmap, const float* __restrict__ kvmap1,
    const float* __restrict__ kvmap2, const float* __restrict__ Wq,
    const float* __restrict__ Wkv, short* __restrict__ Qt,
    short* __restrict__ KV1, short* __restrict__ KV2) {
  const float* in; const float* Wm; short* out; float scale;
  switch (blockIdx.z) {
    case 0:  in = qmap;   Wm = Wq;  out = Qt;  scale = 0.125f; break;
    case 1:  in = kvmap1; Wm = Wkv; out = KV1; scale = 1.0f;   break;
    default: in = kvmap2; Wm = Wkv; out = KV2; scale = 1.0f;   break;
  }
  __shared__ float lin[32][64];
  __shared__ float wl[256][33];
  const int b = blockIdx.y, t = threadIdx.x;
  const int p0 = blockIdx.x * 64;
  const float* inb = in + (size_t)b * CH * HW + p0;
  float acc[64];
  #pragma unroll
  for (int i = 0; i < 64; ++i) acc[i] = 0.f;

  for (int c0 = 0; c0 < CH; c0 += 32) {
    __syncthreads();
    #pragma unroll
    for (int r = 0; r < 8; ++r) {
      int idx = r * 256 + t;
      lin[idx >> 6][idx & 63] = inb[(size_t)(c0 + (idx >> 6)) * HW + (idx & 63)];
    }
    #pragma unroll
    for (int r = 0; r < 32; ++r) {
      int idx = r * 256 + t;
      wl[idx >> 5][idx & 31] = Wm[(size_t)(idx >> 5) * CH + c0 + (idx & 31)];
    }
    __syncthreads();
    for (int cc = 0; cc < 32; ++cc) {
      float wv = wl[t][cc];
      const float4* lp = (const float4*)(&lin[cc][0]);
      #pragma unroll
      for (int k4 = 0; k4 < 16; ++k4) {
        float4 v = lp[k4];
        acc[k4 * 4 + 0] = fmaf(wv, v.x, acc[k4 * 4 + 0]);
        acc[k4 * 4 + 1] = fmaf(wv, v.y, acc[k4 * 4 + 1]);
        acc[k4 * 4 + 2] = fmaf(wv, v.z, acc[k4 * 4 + 2]);
        acc[k4 * 4 + 3] = fmaf(wv, v.w, acc[k4 * 4 + 3]);
      }
    }
  }
  short* ob = out + ((size_t)b * HW + p0) * CH + t;
  #pragma unroll
  for (int p = 0; p < 64; ++p) ob[(size_t)p * CH] = f2bf(acc[p] * scale);
}

// ---------------- MFMA local attention
// block = (tile of 8x8 pixels, b*4+n). 4 waves; wave w owns 16 pixels (nt=w).
// S' = KV x Q^T  (M=pos 224, N=pix 64) -> softmax over pos is lane-local + 2 shfl.
// PV = WT x KVT  (M=pix, N=d, K=pos 224).
__global__ __launch_bounds__(256, 2) void attn_kernel(
    const short* __restrict__ Qt, const short* __restrict__ KV1,
    const short* __restrict__ KV2, float* __restrict__ out) {
  __shared__ char KVT[64 * ROWB];   // [d][pos] bf16, swizzled
  __shared__ char WT [64 * ROWB];   // [pix][pos] bf16, swizzled (wave-private rows)

  const int t = threadIdx.x, lane = t & 63, w = t >> 6;
  const int l15 = lane & 15, lg = lane >> 4;
  const int tile = blockIdx.x;
  const int ty = tile >> 3, tx = tile & 7;
  const int bn = blockIdx.y, b = bn >> 2, n = bn & 3;

  // Q B-fragments for this wave's 16 pixels (pix = w*16 + l15), hoisted
  bf16x8 qf0, qf1;
  {
    int p = w * 16 + l15;
    int gp = (ty * 8 + (p >> 3)) * 64 + tx * 8 + (p & 7);
    const short* qb = Qt + ((size_t)b * HW + gp) * CH + n * DH + lg * 8;
    qf0 = *(const bf16x8*)(qb);
    qf1 = *(const bf16x8*)(qb + 32);
  }

  f32x4 acc2[4];
  #pragma unroll
  for (int i = 0; i < 4; ++i) acc2[i] = (f32x4)0.f;

  const short* kvsrc[2] = {KV1, KV2};
  const int p = w * 16 + l15, py = p >> 3, px = p & 7;

  for (int br = 0; br < 2; ++br) {
    const short* kv = kvsrc[br] + (size_t)b * HW * CH + n * DH;
    if (br) __syncthreads();           // prior PV reads of KVT complete

    // ---- build KVT[d][pos] (cooperative; thread t = pos) ----
    if (t < NPOS) {
      int uy = t >> 4, ux = t & 15;
      int gy = ty * 8 + uy - 3, gx = tx * 8 + ux - 3;
      bool valid = (ux < 14) && (gy >= 0) && (gy < HH) && (gx >= 0) && (gx < WW);
      #pragma unroll
      for (int dc = 0; dc < 8; ++dc) {
        bf16x8 v = (bf16x8)0;
        if (valid) v = *(const bf16x8*)(kv + (size_t)(gy * WW + gx) * CH + dc * 8);
        #pragma unroll
        for (int j = 0; j < 8; ++j) {
          int row = dc * 8 + j;
          *(short*)(KVT + swz(row, row * ROWB + t * 2)) = v[j];
        }
      }
    }
    __syncthreads();                    // KVT ready for all waves

    // ---- S' tiles: A = KV rows (from global, 16B/lane), B = Q frags ----
    f32x4 sa[14];
    #pragma unroll
    for (int mt = 0; mt < 14; ++mt) sa[mt] = (f32x4)0.f;
    {
      int ux = l15;
      int gx = tx * 8 + ux - 3;
      bool xok = (ux < 14) && (gx >= 0) && (gx < WW);
      #pragma unroll 2
      for (int mt = 0; mt < 14; ++mt) {
        int gy = ty * 8 + mt - 3;
        bool valid = xok && (gy >= 0) && (gy < HH);
        bf16x8 a0 = (bf16x8)0, a1 = (bf16x8)0;
        if (valid) {
          const short* src = kv + (size_t)(gy * WW + gx) * CH + lg * 8;
          a0 = *(const bf16x8*)(src);
          a1 = *(const bf16x8*)(src + 32);
        }
        sa[mt] = __builtin_amdgcn_mfma_f32_16x16x32_bf16(a0, qf0, sa[mt], 0, 0, 0);
        sa[mt] = __builtin_amdgcn_mfma_f32_16x16x32_bf16(a1, qf1, sa[mt], 0, 0, 0);
      }
    }

    // ---- masked softmax over pos (lane-local 56 + shfl over lane-groups) ----
    float m = -1e30f;
    #pragma unroll
    for (int mt = 0; mt < 14; ++mt) {
      int dy = mt - py;
      bool yok = (dy >= 0) && (dy <= 6);
      #pragma unroll
      for (int r = 0; r < 4; ++r) {
        int dx = (lg * 4 + r) - px;
        bool in = yok && (dx >= 0) && (dx <= 6);
        float s = in ? sa[mt][r] : -1e30f;
        sa[mt][r] = s;
        m = fmaxf(m, s);
      }
    }
    m = fmaxf(m, __shfl_xor(m, 16, 64));
    m = fmaxf(m, __shfl_xor(m, 32, 64));
    float den = 0.f;
    #pragma unroll
    for (int mt = 0; mt < 14; ++mt) {
      #pragma unroll
      for (int r = 0; r < 4; ++r) {
        float e = __expf(sa[mt][r] - m);   // masked -> exp(-huge) = 0
        sa[mt][r] = e;
        den += e;
      }
    }
    den += __shfl_xor(den, 16, 64);
    den += __shfl_xor(den, 32, 64);
    float inv = 1.f / den;

    // ---- write W^T rows (wave-private; same-wave readback, no barrier) ----
    #pragma unroll
    for (int mt = 0; mt < 14; ++mt) {
      short4_t pk;
      #pragma unroll
      for (int r = 0; r < 4; ++r) pk[r] = f2bf(sa[mt][r] * inv);
      *(short4_t*)(WT + swz(p, p * ROWB + (mt * 16 + lg * 4) * 2)) = pk;
    }

    // ---- PV: O[pix][d] += W^T x KV  (A from WT own rows, B from KVT) ----
    #pragma unroll 1
    for (int kp = 0; kp < 7; ++kp) {
      int posb2 = (kp * 32 + lg * 8) * 2;
      bf16x8 af = *(const bf16x8*)(WT + swz(p, p * ROWB + posb2));
      #pragma unroll
      for (int ntp = 0; ntp < 4; ++ntp) {
        int brow = ntp * 16 + l15;
        bf16x8 bf = *(const bf16x8*)(KVT + swz(brow, brow * ROWB + posb2));
        acc2[ntp] = __builtin_amdgcn_mfma_f32_16x16x32_bf16(af, bf, acc2[ntp], 0, 0, 0);
      }
    }
  }

  // ---- epilogue: average branches, store f32x4 (4 consecutive pixels) ----
  int p0 = w * 16 + lg * 4;
  int gp = (ty * 8 + (p0 >> 3)) * 64 + tx * 8 + (p0 & 7);
  #pragma unroll
  for (int ntp = 0; ntp < 4; ++ntp) {
    int o = n * DH + ntp * 16 + l15;
    f32x4 v = acc2[ntp] * 0.5f;
    *(f32x4*)(out + ((size_t)b * CH + o) * HW + gp) = v;
  }
}

extern "C" void kernel_launch(void* const* d_in, const int* in_sizes, int n_in,
                              void* d_out, int out_size, void* d_ws, size_t ws_size,
                              hipStream_t stream) {
  const float* kvmap1 = (const float*)d_in[0];
  const float* qmap   = (const float*)d_in[1];
  const float* kvmap2 = (const float*)d_in[2];
  const float* Wq     = (const float*)d_in[3];
  const float* Wkv    = (const float*)d_in[4];
  float* out = (float*)d_out;

  // workspace: bf16 Qt | KV1 | KV2, each BB*HW*CH = 2M elems (4 MB) -> 12 MB
  short* Qt  = (short*)d_ws;
  short* KV1 = Qt  + (size_t)BB * HW * CH;
  short* KV2 = KV1 + (size_t)BB * HW * CH;

  dim3 pgrid(HW / 64, BB, 3);
  proj3_kernel<<<pgrid, 256, 0, stream>>>(qmap, kvmap1, kvmap2, Wq, Wkv, Qt, KV1, KV2);

  dim3 agrid(64, BB * HEADS);
  attn_kernel<<<agrid, 256, 0, stream>>>(Qt, KV1, KV2, out);
}

// Round 3
// 115.773 us; speedup vs baseline: 9.8251x; 1.7828x over previous
//
#include <hip/hip_runtime.h>
#include <math.h>

#define HEADS 4
#define DH 64
#define CH 256
#define HW 4096
#define HH 64
#define WW 64
#define BB 2
#define KS 7

#define NPOS 224        // union rows: 14 uy x 16 ux (ux 14,15 are pad, always masked)
#define ROWB 448        // bytes per LDS row (224 bf16)

typedef __attribute__((ext_vector_type(8))) short bf16x8;
typedef __attribute__((ext_vector_type(4))) float f32x4;
typedef __attribute__((ext_vector_type(4))) short short4_t;

__device__ __forceinline__ short f2bf(float x) {
  union { float f; unsigned u; } v; v.f = x;
  unsigned r = (v.u + 0x7fffu + ((v.u >> 16) & 1u)) >> 16;  // RNE
  return (short)r;
}

// XOR swizzle on byte address (write and read sides use the same formula).
__device__ __forceinline__ int swz(int row, int byte_off) {
  return byte_off ^ ((row & 7) << 4);
}

// ---------------- W -> bf16 (Wq gets the q scale folded in; 0.125 is exact) ----
__global__ __launch_bounds__(256) void wcvt_kernel(
    const float* __restrict__ Wq, const float* __restrict__ Wkv,
    short* __restrict__ Wqb, short* __restrict__ Wkvb) {
  const int i = (blockIdx.x * 256 + threadIdx.x) * 4;   // grid.x=64 -> 65536 elems
  const float* src = blockIdx.y ? Wkv : Wq;
  short* dst = blockIdx.y ? Wkvb : Wqb;
  const float sc = blockIdx.y ? 1.0f : 0.125f;
  float4 v = *(const float4*)(src + i);
  short4_t o;
  o.x = f2bf(v.x * sc); o.y = f2bf(v.y * sc);
  o.z = f2bf(v.z * sc); o.w = f2bf(v.w * sc);
  *(short4_t*)(dst + i) = o;
}

// ---------------- MFMA projection: out[b][pix][o] = sum_c in[b][c][pix] * W[o][c]
// grid (HW/64, BB, 3). Block 256 = 4 waves; wave owns 16 pixels x 256 outs.
// A-frags: direct global f32 (lane=pix -> 64B segments), converted to bf16,
// hoisted and reused across all 16 N-tiles. B-frags: 16B bf16 loads (L2-hot).
__global__ __launch_bounds__(256) void proj_mfma_kernel(
    const float* __restrict__ qmap, const float* __restrict__ kvmap1,
    const float* __restrict__ kvmap2, const short* __restrict__ Wqb,
    const short* __restrict__ Wkvb, short* __restrict__ Qt,
    short* __restrict__ KV1, short* __restrict__ KV2) {
  const float* in; const short* Wb; short* out;
  switch (blockIdx.z) {
    case 0:  in = qmap;   Wb = Wqb;  out = Qt;  break;
    case 1:  in = kvmap1; Wb = Wkvb; out = KV1; break;
    default: in = kvmap2; Wb = Wkvb; out = KV2; break;
  }
  const int b = blockIdx.y, t = threadIdx.x;
  const int w = t >> 6, lane = t & 63, l15 = lane & 15, lg = lane >> 4;
  const int pix = blockIdx.x * 64 + w * 16 + l15;       // A-row for this lane
  const float* inb = in + (size_t)b * CH * HW;

  bf16x8 a[8];                                          // k = k8*32 + lg*8 + j
  #pragma unroll
  for (int k8 = 0; k8 < 8; ++k8) {
    #pragma unroll
    for (int j = 0; j < 8; ++j)
      a[k8][j] = f2bf(inb[(size_t)(k8 * 32 + lg * 8 + j) * HW + pix]);
  }

  const int prow = blockIdx.x * 64 + w * 16 + lg * 4;   // C-row base for store
  short* ob = out + (size_t)b * HW * CH;
  #pragma unroll 2
  for (int nt = 0; nt < 16; ++nt) {
    f32x4 acc = (f32x4)0.f;
    const short* wp = Wb + (size_t)(nt * 16 + l15) * CH + lg * 8;
    #pragma unroll
    for (int k8 = 0; k8 < 8; ++k8)
      acc = __builtin_amdgcn_mfma_f32_16x16x32_bf16(
          a[k8], *(const bf16x8*)(wp + k8 * 32), acc, 0, 0, 0);
    #pragma unroll
    for (int r = 0; r < 4; ++r)
      ob[(size_t)(prow + r) * CH + nt * 16 + l15] = f2bf(acc[r]);
  }
}

// ---------------- MFMA local attention (unchanged from round 2)
// block = (tile of 8x8 pixels, b*4+n). 4 waves; wave w owns 16 pixels.
// S' = KV x Q^T  (M=pos 224, N=pix 64) -> softmax over pos is lane-local + 2 shfl.
// PV = WT x KVT  (M=pix, N=d, K=pos 224).
__global__ __launch_bounds__(256, 2) void attn_kernel(
    const short* __restrict__ Qt, const short* __restrict__ KV1,
    const short* __restrict__ KV2, float* __restrict__ out) {
  __shared__ char KVT[64 * ROWB];   // [d][pos] bf16, swizzled
  __shared__ char WT [64 * ROWB];   // [pix][pos] bf16, swizzled (wave-private rows)

  const int t = threadIdx.x, lane = t & 63, w = t >> 6;
  const int l15 = lane & 15, lg = lane >> 4;
  const int tile = blockIdx.x;
  const int ty = tile >> 3, tx = tile & 7;
  const int bn = blockIdx.y, b = bn >> 2, n = bn & 3;

  bf16x8 qf0, qf1;
  {
    int p = w * 16 + l15;
    int gp = (ty * 8 + (p >> 3)) * 64 + tx * 8 + (p & 7);
    const short* qb = Qt + ((size_t)b * HW + gp) * CH + n * DH + lg * 8;
    qf0 = *(const bf16x8*)(qb);
    qf1 = *(const bf16x8*)(qb + 32);
  }

  f32x4 acc2[4];
  #pragma unroll
  for (int i = 0; i < 4; ++i) acc2[i] = (f32x4)0.f;

  const short* kvsrc[2] = {KV1, KV2};
  const int p = w * 16 + l15, py = p >> 3, px = p & 7;

  for (int br = 0; br < 2; ++br) {
    const short* kv = kvsrc[br] + (size_t)b * HW * CH + n * DH;
    if (br) __syncthreads();           // prior PV reads of KVT complete

    // ---- build KVT[d][pos] (cooperative; thread t = pos) ----
    if (t < NPOS) {
      int uy = t >> 4, ux = t & 15;
      int gy = ty * 8 + uy - 3, gx = tx * 8 + ux - 3;
      bool valid = (ux < 14) && (gy >= 0) && (gy < HH) && (gx >= 0) && (gx < WW);
      #pragma unroll
      for (int dc = 0; dc < 8; ++dc) {
        bf16x8 v = (bf16x8)0;
        if (valid) v = *(const bf16x8*)(kv + (size_t)(gy * WW + gx) * CH + dc * 8);
        #pragma unroll
        for (int j = 0; j < 8; ++j) {
          int row = dc * 8 + j;
          *(short*)(KVT + swz(row, row * ROWB + t * 2)) = v[j];
        }
      }
    }
    __syncthreads();                    // KVT ready for all waves

    // ---- S' tiles: A = KV rows (from global, 16B/lane), B = Q frags ----
    f32x4 sa[14];
    #pragma unroll
    for (int mt = 0; mt < 14; ++mt) sa[mt] = (f32x4)0.f;
    {
      int ux = l15;
      int gx = tx * 8 + ux - 3;
      bool xok = (ux < 14) && (gx >= 0) && (gx < WW);
      #pragma unroll 2
      for (int mt = 0; mt < 14; ++mt) {
        int gy = ty * 8 + mt - 3;
        bool valid = xok && (gy >= 0) && (gy < HH);
        bf16x8 a0 = (bf16x8)0, a1 = (bf16x8)0;
        if (valid) {
          const short* src = kv + (size_t)(gy * WW + gx) * CH + lg * 8;
          a0 = *(const bf16x8*)(src);
          a1 = *(const bf16x8*)(src + 32);
        }
        sa[mt] = __builtin_amdgcn_mfma_f32_16x16x32_bf16(a0, qf0, sa[mt], 0, 0, 0);
        sa[mt] = __builtin_amdgcn_mfma_f32_16x16x32_bf16(a1, qf1, sa[mt], 0, 0, 0);
      }
    }

    // ---- masked softmax over pos (lane-local 56 + shfl over lane-groups) ----
    float m = -1e30f;
    #pragma unroll
    for (int mt = 0; mt < 14; ++mt) {
      int dy = mt - py;
      bool yok = (dy >= 0) && (dy <= 6);
      #pragma unroll
      for (int r = 0; r < 4; ++r) {
        int dx = (lg * 4 + r) - px;
        bool in = yok && (dx >= 0) && (dx <= 6);
        float s = in ? sa[mt][r] : -1e30f;
        sa[mt][r] = s;
        m = fmaxf(m, s);
      }
    }
    m = fmaxf(m, __shfl_xor(m, 16, 64));
    m = fmaxf(m, __shfl_xor(m, 32, 64));
    float den = 0.f;
    #pragma unroll
    for (int mt = 0; mt < 14; ++mt) {
      #pragma unroll
      for (int r = 0; r < 4; ++r) {
        float e = __expf(sa[mt][r] - m);   // masked -> exp(-huge) = 0
        sa[mt][r] = e;
        den += e;
      }
    }
    den += __shfl_xor(den, 16, 64);
    den += __shfl_xor(den, 32, 64);
    float inv = 1.f / den;

    // ---- write W^T rows (wave-private; same-wave readback, no barrier) ----
    #pragma unroll
    for (int mt = 0; mt < 14; ++mt) {
      short4_t pk;
      #pragma unroll
      for (int r = 0; r < 4; ++r) pk[r] = f2bf(sa[mt][r] * inv);
      *(short4_t*)(WT + swz(p, p * ROWB + (mt * 16 + lg * 4) * 2)) = pk;
    }

    // ---- PV: O[pix][d] += W^T x KV  (A from WT own rows, B from KVT) ----
    #pragma unroll 1
    for (int kp = 0; kp < 7; ++kp) {
      int posb2 = (kp * 32 + lg * 8) * 2;
      bf16x8 af = *(const bf16x8*)(WT + swz(p, p * ROWB + posb2));
      #pragma unroll
      for (int ntp = 0; ntp < 4; ++ntp) {
        int brow = ntp * 16 + l15;
        bf16x8 bf = *(const bf16x8*)(KVT + swz(brow, brow * ROWB + posb2));
        acc2[ntp] = __builtin_amdgcn_mfma_f32_16x16x32_bf16(af, bf, acc2[ntp], 0, 0, 0);
      }
    }
  }

  // ---- epilogue: average branches, store f32x4 (4 consecutive pixels) ----
  int p0 = w * 16 + lg * 4;
  int gp = (ty * 8 + (p0 >> 3)) * 64 + tx * 8 + (p0 & 7);
  #pragma unroll
  for (int ntp = 0; ntp < 4; ++ntp) {
    int o = n * DH + ntp * 16 + l15;
    f32x4 v = acc2[ntp] * 0.5f;
    *(f32x4*)(out + ((size_t)b * CH + o) * HW + gp) = v;
  }
}

extern "C" void kernel_launch(void* const* d_in, const int* in_sizes, int n_in,
                              void* d_out, int out_size, void* d_ws, size_t ws_size,
                              hipStream_t stream) {
  const float* kvmap1 = (const float*)d_in[0];
  const float* qmap   = (const float*)d_in[1];
  const float* kvmap2 = (const float*)d_in[2];
  const float* Wq     = (const float*)d_in[3];
  const float* Wkv    = (const float*)d_in[4];
  float* out = (float*)d_out;

  // workspace: bf16 Qt | KV1 | KV2 (4 MB each) | Wqb | Wkvb (128 KB each)
  short* Qt   = (short*)d_ws;
  short* KV1  = Qt  + (size_t)BB * HW * CH;
  short* KV2  = KV1 + (size_t)BB * HW * CH;
  short* Wqb  = KV2 + (size_t)BB * HW * CH;
  short* Wkvb = Wqb + (size_t)CH * CH;

  dim3 wgrid(64, 2);
  wcvt_kernel<<<wgrid, 256, 0, stream>>>(Wq, Wkv, Wqb, Wkvb);

  dim3 pgrid(HW / 64, BB, 3);
  proj_mfma_kernel<<<pgrid, 256, 0, stream>>>(qmap, kvmap1, kvmap2, Wqb, Wkvb,
                                              Qt, KV1, KV2);

  dim3 agrid(64, BB * HEADS);
  attn_kernel<<<agrid, 256, 0, stream>>>(Qt, KV1, KV2, out);
}

// Round 4
// 71.453 us; speedup vs baseline: 15.9191x; 1.6203x over previous
//
#include <hip/hip_runtime.h>
#include <math.h>

#define HEADS 4
#define DH 64
#define CH 256
#define HW 4096
#define HH 64
#define WW 64
#define BB 2
#define KS 7

#define NPOS 224        // union rows: 14 uy x 16 ux (ux 14,15 are pad, always masked)
#define ROWB 448        // bytes per LDS row (224 bf16)

typedef __attribute__((ext_vector_type(8))) short bf16x8;
typedef __attribute__((ext_vector_type(4))) float f32x4;
typedef __attribute__((ext_vector_type(4))) short short4_t;

__device__ __forceinline__ short f2bf(float x) {
  union { float f; unsigned u; } v; v.f = x;
  unsigned r = (v.u + 0x7fffu + ((v.u >> 16) & 1u)) >> 16;  // RNE
  return (short)r;
}

// XOR swizzle on byte address (write and read sides use the same formula).
__device__ __forceinline__ int swz(int row, int byte_off) {
  return byte_off ^ ((row & 7) << 4);
}

// ---------------- W -> bf16 (Wq gets the q scale folded in; 0.125 is exact) ----
__global__ __launch_bounds__(256) void wcvt_kernel(
    const float* __restrict__ Wq, const float* __restrict__ Wkv,
    short* __restrict__ Wqb, short* __restrict__ Wkvb) {
  const int i = (blockIdx.x * 256 + threadIdx.x) * 4;   // grid.x=64 -> 65536 elems
  const float* src = blockIdx.y ? Wkv : Wq;
  short* dst = blockIdx.y ? Wkvb : Wqb;
  const float sc = blockIdx.y ? 1.0f : 0.125f;
  float4 v = *(const float4*)(src + i);
  short4_t o;
  o.x = f2bf(v.x * sc); o.y = f2bf(v.y * sc);
  o.z = f2bf(v.z * sc); o.w = f2bf(v.w * sc);
  *(short4_t*)(dst + i) = o;
}

// ---------------- MFMA projection: out[b][pix][o] = sum_c in[b][c][pix] * W[o][c]
// grid (HW/64, BB, 3). Block 256 = 4 waves; wave owns 16 pixels x 256 outs.
__global__ __launch_bounds__(256) void proj_mfma_kernel(
    const float* __restrict__ qmap, const float* __restrict__ kvmap1,
    const float* __restrict__ kvmap2, const short* __restrict__ Wqb,
    const short* __restrict__ Wkvb, short* __restrict__ Qt,
    short* __restrict__ KV1, short* __restrict__ KV2) {
  const float* in; const short* Wb; short* out;
  switch (blockIdx.z) {
    case 0:  in = qmap;   Wb = Wqb;  out = Qt;  break;
    case 1:  in = kvmap1; Wb = Wkvb; out = KV1; break;
    default: in = kvmap2; Wb = Wkvb; out = KV2; break;
  }
  const int b = blockIdx.y, t = threadIdx.x;
  const int w = t >> 6, lane = t & 63, l15 = lane & 15, lg = lane >> 4;
  const int pix = blockIdx.x * 64 + w * 16 + l15;       // A-row for this lane
  const float* inb = in + (size_t)b * CH * HW;

  bf16x8 a[8];                                          // k = k8*32 + lg*8 + j
  #pragma unroll
  for (int k8 = 0; k8 < 8; ++k8) {
    #pragma unroll
    for (int j = 0; j < 8; ++j)
      a[k8][j] = f2bf(inb[(size_t)(k8 * 32 + lg * 8 + j) * HW + pix]);
  }

  const int prow = blockIdx.x * 64 + w * 16 + lg * 4;   // C-row base for store
  short* ob = out + (size_t)b * HW * CH;
  #pragma unroll 2
  for (int nt = 0; nt < 16; ++nt) {
    f32x4 acc = (f32x4)0.f;
    const short* wp = Wb + (size_t)(nt * 16 + l15) * CH + lg * 8;
    #pragma unroll
    for (int k8 = 0; k8 < 8; ++k8)
      acc = __builtin_amdgcn_mfma_f32_16x16x32_bf16(
          a[k8], *(const bf16x8*)(wp + k8 * 32), acc, 0, 0, 0);
    #pragma unroll
    for (int r = 0; r < 4; ++r)
      ob[(size_t)(prow + r) * CH + nt * 16 + l15] = f2bf(acc[r]);
  }
}

// ---------------- MFMA local attention
// block = (tile of 8x8 pixels, b*4+n). 4 waves; wave w owns 16 pixels.
// S' = KV x Q^T  (M=pos 224, N=pix 64) -> softmax over pos is lane-local + 2 shfl.
// PV = WT x KVT  (M=pix, N=d, K=pos 224).
// NOTE: every loop touching sa[] is FULLY unrolled -> sa stays in VGPRs
// (rule #20: runtime-indexed ext_vector arrays go to scratch; the round-3
// "#pragma unroll 2" here cost 283 MB/dispatch of scratch traffic).
__global__ __launch_bounds__(256, 2) void attn_kernel(
    const short* __restrict__ Qt, const short* __restrict__ KV1,
    const short* __restrict__ KV2, float* __restrict__ out) {
  __shared__ char KVT[64 * ROWB];   // [d][pos] bf16, swizzled
  __shared__ char WT [64 * ROWB];   // [pix][pos] bf16, swizzled (wave-private rows)

  const int t = threadIdx.x, lane = t & 63, w = t >> 6;
  const int l15 = lane & 15, lg = lane >> 4;
  const int tile = blockIdx.x;
  const int ty = tile >> 3, tx = tile & 7;
  const int bn = blockIdx.y, b = bn >> 2, n = bn & 3;

  bf16x8 qf0, qf1;
  {
    int p = w * 16 + l15;
    int gp = (ty * 8 + (p >> 3)) * 64 + tx * 8 + (p & 7);
    const short* qb = Qt + ((size_t)b * HW + gp) * CH + n * DH + lg * 8;
    qf0 = *(const bf16x8*)(qb);
    qf1 = *(const bf16x8*)(qb + 32);
  }

  f32x4 acc2[4];
  #pragma unroll
  for (int i = 0; i < 4; ++i) acc2[i] = (f32x4)0.f;

  const int p = w * 16 + l15, py = p >> 3, px = p & 7;

  #pragma unroll
  for (int br = 0; br < 2; ++br) {
    const short* kv = (br ? KV2 : KV1) + (size_t)b * HW * CH + n * DH;
    if (br) __syncthreads();           // prior PV reads of KVT complete

    // ---- build KVT[d][pos] (cooperative; thread t = pos) ----
    if (t < NPOS) {
      int uy = t >> 4, ux = t & 15;
      int gy = ty * 8 + uy - 3, gx = tx * 8 + ux - 3;
      bool valid = (ux < 14) && (gy >= 0) && (gy < HH) && (gx >= 0) && (gx < WW);
      #pragma unroll
      for (int dc = 0; dc < 8; ++dc) {
        bf16x8 v = (bf16x8)0;
        if (valid) v = *(const bf16x8*)(kv + (size_t)(gy * WW + gx) * CH + dc * 8);
        #pragma unroll
        for (int j = 0; j < 8; ++j) {
          int row = dc * 8 + j;
          *(short*)(KVT + swz(row, row * ROWB + t * 2)) = v[j];
        }
      }
    }
    __syncthreads();                    // KVT ready for all waves

    // ---- S' tiles: A = KV rows (from global, 16B/lane), B = Q frags ----
    f32x4 sa[14];
    {
      int ux = l15;
      int gx = tx * 8 + ux - 3;
      bool xok = (ux < 14) && (gx >= 0) && (gx < WW);
      #pragma unroll
      for (int mt = 0; mt < 14; ++mt) {
        int gy = ty * 8 + mt - 3;
        bool valid = xok && (gy >= 0) && (gy < HH);
        bf16x8 a0 = (bf16x8)0, a1 = (bf16x8)0;
        if (valid) {
          const short* src = kv + (size_t)(gy * WW + gx) * CH + lg * 8;
          a0 = *(const bf16x8*)(src);
          a1 = *(const bf16x8*)(src + 32);
        }
        f32x4 s = (f32x4)0.f;
        s = __builtin_amdgcn_mfma_f32_16x16x32_bf16(a0, qf0, s, 0, 0, 0);
        s = __builtin_amdgcn_mfma_f32_16x16x32_bf16(a1, qf1, s, 0, 0, 0);
        sa[mt] = s;
      }
    }

    // ---- masked softmax over pos (lane-local 56 + shfl over lane-groups) ----
    float m = -1e30f;
    #pragma unroll
    for (int mt = 0; mt < 14; ++mt) {
      int dy = mt - py;
      bool yok = (dy >= 0) && (dy <= 6);
      #pragma unroll
      for (int r = 0; r < 4; ++r) {
        int dx = (lg * 4 + r) - px;
        bool in = yok && (dx >= 0) && (dx <= 6);
        float s = in ? sa[mt][r] : -1e30f;
        sa[mt][r] = s;
        m = fmaxf(m, s);
      }
    }
    m = fmaxf(m, __shfl_xor(m, 16, 64));
    m = fmaxf(m, __shfl_xor(m, 32, 64));
    float den = 0.f;
    #pragma unroll
    for (int mt = 0; mt < 14; ++mt) {
      #pragma unroll
      for (int r = 0; r < 4; ++r) {
        float e = __expf(sa[mt][r] - m);   // masked -> exp(-huge) = 0
        sa[mt][r] = e;
        den += e;
      }
    }
    den += __shfl_xor(den, 16, 64);
    den += __shfl_xor(den, 32, 64);
    float inv = 1.f / den;

    // ---- write W^T rows (wave-private; same-wave readback, no barrier) ----
    #pragma unroll
    for (int mt = 0; mt < 14; ++mt) {
      short4_t pk;
      #pragma unroll
      for (int r = 0; r < 4; ++r) pk[r] = f2bf(sa[mt][r] * inv);
      *(short4_t*)(WT + swz(p, p * ROWB + (mt * 16 + lg * 4) * 2)) = pk;
    }

    // ---- PV: O[pix][d] += W^T x KV  (A from WT own rows, B from KVT) ----
    #pragma unroll 1
    for (int kp = 0; kp < 7; ++kp) {
      int posb2 = (kp * 32 + lg * 8) * 2;
      bf16x8 af = *(const bf16x8*)(WT + swz(p, p * ROWB + posb2));
      #pragma unroll
      for (int ntp = 0; ntp < 4; ++ntp) {
        int brow = ntp * 16 + l15;
        bf16x8 bf = *(const bf16x8*)(KVT + swz(brow, brow * ROWB + posb2));
        acc2[ntp] = __builtin_amdgcn_mfma_f32_16x16x32_bf16(af, bf, acc2[ntp], 0, 0, 0);
      }
    }
  }

  // ---- epilogue: average branches, store f32x4 (4 consecutive pixels) ----
  int p0 = w * 16 + lg * 4;
  int gp = (ty * 8 + (p0 >> 3)) * 64 + tx * 8 + (p0 & 7);
  #pragma unroll
  for (int ntp = 0; ntp < 4; ++ntp) {
    int o = n * DH + ntp * 16 + l15;
    f32x4 v = acc2[ntp] * 0.5f;
    *(f32x4*)(out + ((size_t)b * CH + o) * HW + gp) = v;
  }
}

extern "C" void kernel_launch(void* const* d_in, const int* in_sizes, int n_in,
                              void* d_out, int out_size, void* d_ws, size_t ws_size,
                              hipStream_t stream) {
  const float* kvmap1 = (const float*)d_in[0];
  const float* qmap   = (const float*)d_in[1];
  const float* kvmap2 = (const float*)d_in[2];
  const float* Wq     = (const float*)d_in[3];
  const float* Wkv    = (const float*)d_in[4];
  float* out = (float*)d_out;

  // workspace: bf16 Qt | KV1 | KV2 (4 MB each) | Wqb | Wkvb (128 KB each)
  short* Qt   = (short*)d_ws;
  short* KV1  = Qt  + (size_t)BB * HW * CH;
  short* KV2  = KV1 + (size_t)BB * HW * CH;
  short* Wqb  = KV2 + (size_t)BB * HW * CH;
  short* Wkvb = Wqb + (size_t)CH * CH;

  dim3 wgrid(64, 2);
  wcvt_kernel<<<wgrid, 256, 0, stream>>>(Wq, Wkv, Wqb, Wkvb);

  dim3 pgrid(HW / 64, BB, 3);
  proj_mfma_kernel<<<pgrid, 256, 0, stream>>>(qmap, kvmap1, kvmap2, Wqb, Wkvb,
                                              Qt, KV1, KV2);

  dim3 agrid(64, BB * HEADS);
  attn_kernel<<<agrid, 256, 0, stream>>>(Qt, KV1, KV2, out);
}

// Round 5
// 63.693 us; speedup vs baseline: 17.8587x; 1.1218x over previous
//
#include <hip/hip_runtime.h>
#include <math.h>

#define HEADS 4
#define DH 64
#define CH 256
#define HW 4096
#define HH 64
#define WW 64
#define BB 2
#define KS 7

#define NPOS 224        // union rows: 14 uy x 16 ux (ux 14,15 are pad, always masked)
#define ROWB 448        // bytes per LDS row (224 bf16)

typedef __attribute__((ext_vector_type(8))) short bf16x8;
typedef __attribute__((ext_vector_type(4))) float f32x4;
typedef __attribute__((ext_vector_type(4))) short short4_t;

__device__ __forceinline__ short f2bf(float x) {
  union { float f; unsigned u; } v; v.f = x;
  unsigned r = (v.u + 0x7fffu + ((v.u >> 16) & 1u)) >> 16;  // RNE
  return (short)r;
}

// XOR swizzle on byte address (write and read sides use the same formula).
__device__ __forceinline__ int swz(int row, int byte_off) {
  return byte_off ^ ((row & 7) << 4);
}

// ---------------- W -> bf16 (Wq gets the q scale folded in; 0.125 is exact) ----
__global__ __launch_bounds__(256) void wcvt_kernel(
    const float* __restrict__ Wq, const float* __restrict__ Wkv,
    short* __restrict__ Wqb, short* __restrict__ Wkvb) {
  const int i = (blockIdx.x * 256 + threadIdx.x) * 4;   // grid.x=64 -> 65536 elems
  const float* src = blockIdx.y ? Wkv : Wq;
  short* dst = blockIdx.y ? Wkvb : Wqb;
  const float sc = blockIdx.y ? 1.0f : 0.125f;
  float4 v = *(const float4*)(src + i);
  short4_t o;
  o.x = f2bf(v.x * sc); o.y = f2bf(v.y * sc);
  o.z = f2bf(v.z * sc); o.w = f2bf(v.w * sc);
  *(short4_t*)(dst + i) = o;
}

// ---------------- MFMA projection: out[b][pix][o] = sum_c in[b][c][pix] * W[o][c]
// grid (HW/64, BB, 12): z = input*4 + out-channel-group. Block 256 = 4 waves;
// wave owns 16 pixels x 64 outs (4 N-tiles). 4x round-4 grid -> 6 waves/SIMD
// (round 4: 1.5 waves/SIMD, fully latency-exposed A gather). A re-gathered 4x
// (96 MB, L2/L3-hot, ~3 us of L2 BW) -- cheap vs the latency win.
__global__ __launch_bounds__(256) void proj_mfma_kernel(
    const float* __restrict__ qmap, const float* __restrict__ kvmap1,
    const float* __restrict__ kvmap2, const short* __restrict__ Wqb,
    const short* __restrict__ Wkvb, short* __restrict__ Qt,
    short* __restrict__ KV1, short* __restrict__ KV2) {
  const float* in; const short* Wb; short* out;
  switch (blockIdx.z >> 2) {
    case 0:  in = qmap;   Wb = Wqb;  out = Qt;  break;
    case 1:  in = kvmap1; Wb = Wkvb; out = KV1; break;
    default: in = kvmap2; Wb = Wkvb; out = KV2; break;
  }
  const int ng = blockIdx.z & 3;                        // out-channel group (64)
  const int b = blockIdx.y, t = threadIdx.x;
  const int w = t >> 6, lane = t & 63, l15 = lane & 15, lg = lane >> 4;
  const int pix = blockIdx.x * 64 + w * 16 + l15;       // A-row for this lane
  const float* inb = in + (size_t)b * CH * HW;

  bf16x8 a[8];                                          // k = k8*32 + lg*8 + j
  #pragma unroll
  for (int k8 = 0; k8 < 8; ++k8) {
    #pragma unroll
    for (int j = 0; j < 8; ++j)
      a[k8][j] = f2bf(inb[(size_t)(k8 * 32 + lg * 8 + j) * HW + pix]);
  }

  const int prow = blockIdx.x * 64 + w * 16 + lg * 4;   // C-row base for store
  short* ob = out + (size_t)b * HW * CH;
  #pragma unroll
  for (int nq = 0; nq < 4; ++nq) {
    const int nt = ng * 4 + nq;
    f32x4 acc = (f32x4)0.f;
    const short* wp = Wb + (size_t)(nt * 16 + l15) * CH + lg * 8;
    #pragma unroll
    for (int k8 = 0; k8 < 8; ++k8)
      acc = __builtin_amdgcn_mfma_f32_16x16x32_bf16(
          a[k8], *(const bf16x8*)(wp + k8 * 32), acc, 0, 0, 0);
    #pragma unroll
    for (int r = 0; r < 4; ++r)
      ob[(size_t)(prow + r) * CH + nt * 16 + l15] = f2bf(acc[r]);
  }
}

// ---------------- MFMA local attention (unchanged from round 4)
// block = (tile of 8x8 pixels, b*4+n). 4 waves; wave w owns 16 pixels.
// S' = KV x Q^T  (M=pos 224, N=pix 64) -> softmax over pos is lane-local + 2 shfl.
// PV = WT x KVT  (M=pix, N=d, K=pos 224).
// NOTE: every loop touching sa[] is FULLY unrolled -> sa stays in VGPRs
// (rule #20: runtime-indexed ext_vector arrays go to scratch).
__global__ __launch_bounds__(256, 2) void attn_kernel(
    const short* __restrict__ Qt, const short* __restrict__ KV1,
    const short* __restrict__ KV2, float* __restrict__ out) {
  __shared__ char KVT[64 * ROWB];   // [d][pos] bf16, swizzled
  __shared__ char WT [64 * ROWB];   // [pix][pos] bf16, swizzled (wave-private rows)

  const int t = threadIdx.x, lane = t & 63, w = t >> 6;
  const int l15 = lane & 15, lg = lane >> 4;
  const int tile = blockIdx.x;
  const int ty = tile >> 3, tx = tile & 7;
  const int bn = blockIdx.y, b = bn >> 2, n = bn & 3;

  bf16x8 qf0, qf1;
  {
    int p = w * 16 + l15;
    int gp = (ty * 8 + (p >> 3)) * 64 + tx * 8 + (p & 7);
    const short* qb = Qt + ((size_t)b * HW + gp) * CH + n * DH + lg * 8;
    qf0 = *(const bf16x8*)(qb);
    qf1 = *(const bf16x8*)(qb + 32);
  }

  f32x4 acc2[4];
  #pragma unroll
  for (int i = 0; i < 4; ++i) acc2[i] = (f32x4)0.f;

  const int p = w * 16 + l15, py = p >> 3, px = p & 7;

  #pragma unroll
  for (int br = 0; br < 2; ++br) {
    const short* kv = (br ? KV2 : KV1) + (size_t)b * HW * CH + n * DH;
    if (br) __syncthreads();           // prior PV reads of KVT complete

    // ---- build KVT[d][pos] (cooperative; thread t = pos) ----
    if (t < NPOS) {
      int uy = t >> 4, ux = t & 15;
      int gy = ty * 8 + uy - 3, gx = tx * 8 + ux - 3;
      bool valid = (ux < 14) && (gy >= 0) && (gy < HH) && (gx >= 0) && (gx < WW);
      #pragma unroll
      for (int dc = 0; dc < 8; ++dc) {
        bf16x8 v = (bf16x8)0;
        if (valid) v = *(const bf16x8*)(kv + (size_t)(gy * WW + gx) * CH + dc * 8);
        #pragma unroll
        for (int j = 0; j < 8; ++j) {
          int row = dc * 8 + j;
          *(short*)(KVT + swz(row, row * ROWB + t * 2)) = v[j];
        }
      }
    }
    __syncthreads();                    // KVT ready for all waves

    // ---- S' tiles: A = KV rows (from global, 16B/lane), B = Q frags ----
    f32x4 sa[14];
    {
      int ux = l15;
      int gx = tx * 8 + ux - 3;
      bool xok = (ux < 14) && (gx >= 0) && (gx < WW);
      #pragma unroll
      for (int mt = 0; mt < 14; ++mt) {
        int gy = ty * 8 + mt - 3;
        bool valid = xok && (gy >= 0) && (gy < HH);
        bf16x8 a0 = (bf16x8)0, a1 = (bf16x8)0;
        if (valid) {
          const short* src = kv + (size_t)(gy * WW + gx) * CH + lg * 8;
          a0 = *(const bf16x8*)(src);
          a1 = *(const bf16x8*)(src + 32);
        }
        f32x4 s = (f32x4)0.f;
        s = __builtin_amdgcn_mfma_f32_16x16x32_bf16(a0, qf0, s, 0, 0, 0);
        s = __builtin_amdgcn_mfma_f32_16x16x32_bf16(a1, qf1, s, 0, 0, 0);
        sa[mt] = s;
      }
    }

    // ---- masked softmax over pos (lane-local 56 + shfl over lane-groups) ----
    float m = -1e30f;
    #pragma unroll
    for (int mt = 0; mt < 14; ++mt) {
      int dy = mt - py;
      bool yok = (dy >= 0) && (dy <= 6);
      #pragma unroll
      for (int r = 0; r < 4; ++r) {
        int dx = (lg * 4 + r) - px;
        bool in = yok && (dx >= 0) && (dx <= 6);
        float s = in ? sa[mt][r] : -1e30f;
        sa[mt][r] = s;
        m = fmaxf(m, s);
      }
    }
    m = fmaxf(m, __shfl_xor(m, 16, 64));
    m = fmaxf(m, __shfl_xor(m, 32, 64));
    float den = 0.f;
    #pragma unroll
    for (int mt = 0; mt < 14; ++mt) {
      #pragma unroll
      for (int r = 0; r < 4; ++r) {
        float e = __expf(sa[mt][r] - m);   // masked -> exp(-huge) = 0
        sa[mt][r] = e;
        den += e;
      }
    }
    den += __shfl_xor(den, 16, 64);
    den += __shfl_xor(den, 32, 64);
    float inv = 1.f / den;

    // ---- write W^T rows (wave-private; same-wave readback, no barrier) ----
    #pragma unroll
    for (int mt = 0; mt < 14; ++mt) {
      short4_t pk;
      #pragma unroll
      for (int r = 0; r < 4; ++r) pk[r] = f2bf(sa[mt][r] * inv);
      *(short4_t*)(WT + swz(p, p * ROWB + (mt * 16 + lg * 4) * 2)) = pk;
    }

    // ---- PV: O[pix][d] += W^T x KV  (A from WT own rows, B from KVT) ----
    #pragma unroll 1
    for (int kp = 0; kp < 7; ++kp) {
      int posb2 = (kp * 32 + lg * 8) * 2;
      bf16x8 af = *(const bf16x8*)(WT + swz(p, p * ROWB + posb2));
      #pragma unroll
      for (int ntp = 0; ntp < 4; ++ntp) {
        int brow = ntp * 16 + l15;
        bf16x8 bf = *(const bf16x8*)(KVT + swz(brow, brow * ROWB + posb2));
        acc2[ntp] = __builtin_amdgcn_mfma_f32_16x16x32_bf16(af, bf, acc2[ntp], 0, 0, 0);
      }
    }
  }

  // ---- epilogue: average branches, store f32x4 (4 consecutive pixels) ----
  int p0 = w * 16 + lg * 4;
  int gp = (ty * 8 + (p0 >> 3)) * 64 + tx * 8 + (p0 & 7);
  #pragma unroll
  for (int ntp = 0; ntp < 4; ++ntp) {
    int o = n * DH + ntp * 16 + l15;
    f32x4 v = acc2[ntp] * 0.5f;
    *(f32x4*)(out + ((size_t)b * CH + o) * HW + gp) = v;
  }
}

extern "C" void kernel_launch(void* const* d_in, const int* in_sizes, int n_in,
                              void* d_out, int out_size, void* d_ws, size_t ws_size,
                              hipStream_t stream) {
  const float* kvmap1 = (const float*)d_in[0];
  const float* qmap   = (const float*)d_in[1];
  const float* kvmap2 = (const float*)d_in[2];
  const float* Wq     = (const float*)d_in[3];
  const float* Wkv    = (const float*)d_in[4];
  float* out = (float*)d_out;

  // workspace: bf16 Qt | KV1 | KV2 (4 MB each) | Wqb | Wkvb (128 KB each)
  short* Qt   = (short*)d_ws;
  short* KV1  = Qt  + (size_t)BB * HW * CH;
  short* KV2  = KV1 + (size_t)BB * HW * CH;
  short* Wqb  = KV2 + (size_t)BB * HW * CH;
  short* Wkvb = Wqb + (size_t)CH * CH;

  dim3 wgrid(64, 2);
  wcvt_kernel<<<wgrid, 256, 0, stream>>>(Wq, Wkv, Wqb, Wkvb);

  dim3 pgrid(HW / 64, BB, 12);
  proj_mfma_kernel<<<pgrid, 256, 0, stream>>>(qmap, kvmap1, kvmap2, Wqb, Wkvb,
                                              Qt, KV1, KV2);

  dim3 agrid(64, BB * HEADS);
  attn_kernel<<<agrid, 256, 0, stream>>>(Qt, KV1, KV2, out);
}

// Round 6
// 59.363 us; speedup vs baseline: 19.1613x; 1.0729x over previous
//
#include <hip/hip_runtime.h>
#include <math.h>

#define HEADS 4
#define DH 64
#define CH 256
#define HW 4096
#define HH 64
#define WW 64
#define BB 2
#define KS 7

#define NPOS 224        // union rows: 14 uy x 16 ux (ux 14,15 are pad, always masked)
#define ROWB 448        // bytes per KVT LDS row (224 bf16)
#define WROWB 256       // bytes per WT LDS row (128 bf16: wave-local 8 uy rows)

typedef __attribute__((ext_vector_type(8))) short bf16x8;
typedef __attribute__((ext_vector_type(4))) float f32x4;
typedef __attribute__((ext_vector_type(4))) short short4_t;

__device__ __forceinline__ short f2bf(float x) {
  union { float f; unsigned u; } v; v.f = x;
  unsigned r = (v.u + 0x7fffu + ((v.u >> 16) & 1u)) >> 16;  // RNE
  return (short)r;
}

// XOR swizzle on byte address (write and read sides use the same formula).
__device__ __forceinline__ int swz(int row, int byte_off) {
  return byte_off ^ ((row & 7) << 4);
}

// ---------------- W -> bf16 (Wq gets the q scale folded in; 0.125 is exact) ----
__global__ __launch_bounds__(256) void wcvt_kernel(
    const float* __restrict__ Wq, const float* __restrict__ Wkv,
    short* __restrict__ Wqb, short* __restrict__ Wkvb) {
  const int i = (blockIdx.x * 256 + threadIdx.x) * 4;   // grid.x=64 -> 65536 elems
  const float* src = blockIdx.y ? Wkv : Wq;
  short* dst = blockIdx.y ? Wkvb : Wqb;
  const float sc = blockIdx.y ? 1.0f : 0.125f;
  float4 v = *(const float4*)(src + i);
  short4_t o;
  o.x = f2bf(v.x * sc); o.y = f2bf(v.y * sc);
  o.z = f2bf(v.z * sc); o.w = f2bf(v.w * sc);
  *(short4_t*)(dst + i) = o;
}

// ---------------- MFMA projection: out[b][pix][o] = sum_c in[b][c][pix] * W[o][c]
// grid (HW/64, BB, 12): z = input*4 + out-channel-group. Block 256 = 4 waves;
// wave owns 16 pixels x 64 outs (4 N-tiles).
// A-gather: 32 f32 loads batched into named regs BEFORE converting (round-5
// version at VGPR=60 serialized the 64 loads into ~8 latency rounds).
__global__ __launch_bounds__(256, 4) void proj_mfma_kernel(
    const float* __restrict__ qmap, const float* __restrict__ kvmap1,
    const float* __restrict__ kvmap2, const short* __restrict__ Wqb,
    const short* __restrict__ Wkvb, short* __restrict__ Qt,
    short* __restrict__ KV1, short* __restrict__ KV2) {
  const float* in; const short* Wb; short* out;
  switch (blockIdx.z >> 2) {
    case 0:  in = qmap;   Wb = Wqb;  out = Qt;  break;
    case 1:  in = kvmap1; Wb = Wkvb; out = KV1; break;
    default: in = kvmap2; Wb = Wkvb; out = KV2; break;
  }
  const int ng = blockIdx.z & 3;                        // out-channel group (64)
  const int b = blockIdx.y, t = threadIdx.x;
  const int w = t >> 6, lane = t & 63, l15 = lane & 15, lg = lane >> 4;
  const int pix = blockIdx.x * 64 + w * 16 + l15;       // A-row for this lane
  const float* inb = in + (size_t)b * CH * HW;

  bf16x8 a[8];                                          // k8: c = k8*32 + lg*8 + j
  #pragma unroll
  for (int h = 0; h < 2; ++h) {
    float av[32];
    #pragma unroll
    for (int k = 0; k < 32; ++k)                        // 32 loads in flight
      av[k] = inb[(size_t)(h * 128 + (k >> 3) * 32 + lg * 8 + (k & 7)) * HW + pix];
    #pragma unroll
    for (int k8 = 0; k8 < 4; ++k8)
      #pragma unroll
      for (int j = 0; j < 8; ++j)
        a[h * 4 + k8][j] = f2bf(av[k8 * 8 + j]);
  }

  const int prow = blockIdx.x * 64 + w * 16 + lg * 4;   // C-row base for store
  short* ob = out + (size_t)b * HW * CH;
  #pragma unroll
  for (int nq = 0; nq < 4; ++nq) {
    const int nt = ng * 4 + nq;
    f32x4 acc = (f32x4)0.f;
    const short* wp = Wb + (size_t)(nt * 16 + l15) * CH + lg * 8;
    #pragma unroll
    for (int k8 = 0; k8 < 8; ++k8)
      acc = __builtin_amdgcn_mfma_f32_16x16x32_bf16(
          a[k8], *(const bf16x8*)(wp + k8 * 32), acc, 0, 0, 0);
    #pragma unroll
    for (int r = 0; r < 4; ++r)
      ob[(size_t)(prow + r) * CH + nt * 16 + l15] = f2bf(acc[r]);
  }
}

// ---------------- MFMA local attention
// block = (8x8 pixel tile, b*4+n). 4 waves; wave w owns 16 pixels (tile rows
// 2w, 2w+1). KEY: those pixels' 7x7 windows only touch union rows
// mt in [2w, 2w+7] -> each wave computes ONLY its 8 S' row-tiles and
// contracts PV over K=128 (was: all 14 rows / K=224, rest masked to zero).
// Bit-identical (masked pos had P=0). WT shrinks to 64x128 -> LDS 44 KB ->
// 3 blocks/CU (was 2).
__global__ __launch_bounds__(256, 3) void attn_kernel(
    const short* __restrict__ Qt, const short* __restrict__ KV1,
    const short* __restrict__ KV2, float* __restrict__ out) {
  __shared__ char KVT[64 * ROWB];    // [d][pos 224] bf16, swizzled (28 KB)
  __shared__ char WT [64 * WROWB];   // [pix][pos_local 128] bf16, swizzled (16 KB)

  const int t = threadIdx.x, lane = t & 63, w = t >> 6;
  const int l15 = lane & 15, lg = lane >> 4;
  const int tile = blockIdx.x;
  const int ty = tile >> 3, tx = tile & 7;
  const int bn = blockIdx.y, b = bn >> 2, n = bn & 3;

  bf16x8 qf0, qf1;
  {
    int p = w * 16 + l15;
    int gp = (ty * 8 + (p >> 3)) * 64 + tx * 8 + (p & 7);
    const short* qb = Qt + ((size_t)b * HW + gp) * CH + n * DH + lg * 8;
    qf0 = *(const bf16x8*)(qb);
    qf1 = *(const bf16x8*)(qb + 32);
  }

  f32x4 acc2[4];
  #pragma unroll
  for (int i = 0; i < 4; ++i) acc2[i] = (f32x4)0.f;

  const int p = w * 16 + l15, px = p & 7;
  const int hi8 = l15 >> 3;              // pixel row within wave pair: py = 2w+hi8

  #pragma unroll
  for (int br = 0; br < 2; ++br) {
    const short* kv = (br ? KV2 : KV1) + (size_t)b * HW * CH + n * DH;
    if (br) __syncthreads();           // prior PV reads of KVT complete

    // ---- build KVT[d][pos] (cooperative; thread t = pos) ----
    if (t < NPOS) {
      int uy = t >> 4, ux = t & 15;
      int gy = ty * 8 + uy - 3, gx = tx * 8 + ux - 3;
      bool valid = (ux < 14) && (gy >= 0) && (gy < HH) && (gx >= 0) && (gx < WW);
      #pragma unroll
      for (int dc = 0; dc < 8; ++dc) {
        bf16x8 v = (bf16x8)0;
        if (valid) v = *(const bf16x8*)(kv + (size_t)(gy * WW + gx) * CH + dc * 8);
        #pragma unroll
        for (int j = 0; j < 8; ++j) {
          int row = dc * 8 + j;
          *(short*)(KVT + swz(row, row * ROWB + t * 2)) = v[j];
        }
      }
    }
    __syncthreads();                    // KVT ready for all waves

    // ---- S' tiles, wave-local rows mt = 2w+i, i=0..7 ----
    f32x4 sa[8];
    {
      int ux = l15;
      int gx = tx * 8 + ux - 3;
      bool xok = (ux < 14) && (gx >= 0) && (gx < WW);
      #pragma unroll
      for (int i = 0; i < 8; ++i) {
        int gy = ty * 8 + (2 * w + i) - 3;
        bool valid = xok && (gy >= 0) && (gy < HH);
        bf16x8 a0 = (bf16x8)0, a1 = (bf16x8)0;
        if (valid) {
          const short* src = kv + (size_t)(gy * WW + gx) * CH + lg * 8;
          a0 = *(const bf16x8*)(src);
          a1 = *(const bf16x8*)(src + 32);
        }
        f32x4 s = (f32x4)0.f;
        s = __builtin_amdgcn_mfma_f32_16x16x32_bf16(a0, qf0, s, 0, 0, 0);
        s = __builtin_amdgcn_mfma_f32_16x16x32_bf16(a1, qf1, s, 0, 0, 0);
        sa[i] = s;
      }
    }

    // ---- masked softmax over pos (32 lane-local + shfl over lane-groups) ----
    float m = -1e30f;
    #pragma unroll
    for (int i = 0; i < 8; ++i) {
      int dy = i - hi8;                  // (2w+i) - py
      bool yok = (dy >= 0) && (dy <= 6);
      #pragma unroll
      for (int r = 0; r < 4; ++r) {
        int dx = (lg * 4 + r) - px;
        bool in = yok && (dx >= 0) && (dx <= 6);
        float s = in ? sa[i][r] : -1e30f;
        sa[i][r] = s;
        m = fmaxf(m, s);
      }
    }
    m = fmaxf(m, __shfl_xor(m, 16, 64));
    m = fmaxf(m, __shfl_xor(m, 32, 64));
    float den = 0.f;
    #pragma unroll
    for (int i = 0; i < 8; ++i) {
      #pragma unroll
      for (int r = 0; r < 4; ++r) {
        float e = __expf(sa[i][r] - m);   // masked -> exp(-huge) = 0
        sa[i][r] = e;
        den += e;
      }
    }
    den += __shfl_xor(den, 16, 64);
    den += __shfl_xor(den, 32, 64);
    float inv = 1.f / den;

    // ---- write W^T rows, local cols (wave-private; same-wave readback) ----
    #pragma unroll
    for (int i = 0; i < 8; ++i) {
      short4_t pk;
      #pragma unroll
      for (int r = 0; r < 4; ++r) pk[r] = f2bf(sa[i][r] * inv);
      *(short4_t*)(WT + swz(p, p * WROWB + (i * 16 + lg * 4) * 2)) = pk;
    }

    // ---- PV: O[pix][d] += W^T x KV, K = 128 wave-local positions ----
    #pragma unroll 1
    for (int kp = 0; kp < 4; ++kp) {
      int lposb = (kp * 32 + lg * 8) * 2;            // WT local col byte
      int gposb = (32 * w + kp * 32 + lg * 8) * 2;   // KVT global pos byte
      bf16x8 af = *(const bf16x8*)(WT + swz(p, p * WROWB + lposb));
      #pragma unroll
      for (int ntp = 0; ntp < 4; ++ntp) {
        int brow = ntp * 16 + l15;
        bf16x8 bf = *(const bf16x8*)(KVT + swz(brow, brow * ROWB + gposb));
        acc2[ntp] = __builtin_amdgcn_mfma_f32_16x16x32_bf16(af, bf, acc2[ntp], 0, 0, 0);
      }
    }
  }

  // ---- epilogue: average branches, store f32x4 (4 consecutive pixels) ----
  int p0 = w * 16 + lg * 4;
  int gp = (ty * 8 + (p0 >> 3)) * 64 + tx * 8 + (p0 & 7);
  #pragma unroll
  for (int ntp = 0; ntp < 4; ++ntp) {
    int o = n * DH + ntp * 16 + l15;
    f32x4 v = acc2[ntp] * 0.5f;
    *(f32x4*)(out + ((size_t)b * CH + o) * HW + gp) = v;
  }
}

extern "C" void kernel_launch(void* const* d_in, const int* in_sizes, int n_in,
                              void* d_out, int out_size, void* d_ws, size_t ws_size,
                              hipStream_t stream) {
  const float* kvmap1 = (const float*)d_in[0];
  const float* qmap   = (const float*)d_in[1];
  const float* kvmap2 = (const float*)d_in[2];
  const float* Wq     = (const float*)d_in[3];
  const float* Wkv    = (const float*)d_in[4];
  float* out = (float*)d_out;

  // workspace: bf16 Qt | KV1 | KV2 (4 MB each) | Wqb | Wkvb (128 KB each)
  short* Qt   = (short*)d_ws;
  short* KV1  = Qt  + (size_t)BB * HW * CH;
  short* KV2  = KV1 + (size_t)BB * HW * CH;
  short* Wqb  = KV2 + (size_t)BB * HW * CH;
  short* Wkvb = Wqb + (size_t)CH * CH;

  dim3 wgrid(64, 2);
  wcvt_kernel<<<wgrid, 256, 0, stream>>>(Wq, Wkv, Wqb, Wkvb);

  dim3 pgrid(HW / 64, BB, 12);
  proj_mfma_kernel<<<pgrid, 256, 0, stream>>>(qmap, kvmap1, kvmap2, Wqb, Wkvb,
                                              Qt, KV1, KV2);

  dim3 agrid(64, BB * HEADS);
  attn_kernel<<<agrid, 256, 0, stream>>>(Qt, KV1, KV2, out);
}

// Round 7
// 40.122 us; speedup vs baseline: 28.3505x; 1.4796x over previous
//
#include <hip/hip_runtime.h>
#include <hip/hip_bf16.h>
#include <math.h>

#define HEADS 4
#define DH 64
#define CH 256
#define HW 4096
#define HH 64
#define WW 64
#define BB 2
#define KS 7

#define NPOS 224        // union rows: 14 uy x 16 ux (ux 14,15 are pad, always masked)
#define ROWB 448        // bytes per KVT LDS row (224 bf16)
#define WROWB 256       // bytes per WT LDS row (128 bf16: wave-local 8 uy rows)

typedef __attribute__((ext_vector_type(8))) short bf16x8;
typedef __attribute__((ext_vector_type(4))) float f32x4;
typedef __attribute__((ext_vector_type(4))) short short4_t;

__device__ __forceinline__ short f2bf(float x) {
  union { float f; unsigned u; } v; v.f = x;
  unsigned r = (v.u + 0x7fffu + ((v.u >> 16) & 1u)) >> 16;  // RNE
  return (short)r;
}

// XOR swizzle on byte address (write and read sides use the same formula).
__device__ __forceinline__ int swz(int row, int byte_off) {
  return byte_off ^ ((row & 7) << 4);
}

// ---------------- W -> bf16 (Wq gets the q scale folded in; 0.125 is exact) ----
__global__ __launch_bounds__(256) void wcvt_kernel(
    const float* __restrict__ Wq, const float* __restrict__ Wkv,
    short* __restrict__ Wqb, short* __restrict__ Wkvb) {
  const int i = (blockIdx.x * 256 + threadIdx.x) * 4;   // grid.x=64 -> 65536 elems
  const float* src = blockIdx.y ? Wkv : Wq;
  short* dst = blockIdx.y ? Wkvb : Wqb;
  const float sc = blockIdx.y ? 1.0f : 0.125f;
  float4 v = *(const float4*)(src + i);
  short4_t o;
  o.x = f2bf(v.x * sc); o.y = f2bf(v.y * sc);
  o.z = f2bf(v.z * sc); o.w = f2bf(v.w * sc);
  *(short4_t*)(dst + i) = o;
}

// ---------------- MFMA projection: out[b][pix][o] = sum_c in[b][c][pix] * W[o][c]
// grid (HW/64, BB, 12): z = input*4 + out-channel-group. Block 256 = 4 waves;
// wave owns 16 pixels x 64 outs (4 N-tiles).
// Round-7 fix: the direct-global B-fragment loads were 64 x 16B segments PER
// INSTRUCTION (16 rows x stride 512B x 4 chunks) -> ~2048 segment-requests
// per wave on the TA pipe. Stage the 64x256 W-slice in LDS (coalesced b128,
// XOR-swizzled rows) and read fragments from LDS instead (2-way = free).
__global__ __launch_bounds__(256) void proj_mfma_kernel(
    const float* __restrict__ qmap, const float* __restrict__ kvmap1,
    const float* __restrict__ kvmap2, const short* __restrict__ Wqb,
    const short* __restrict__ Wkvb, short* __restrict__ Qt,
    short* __restrict__ KV1, short* __restrict__ KV2) {
  const float* in; const short* Wb; short* out;
  switch (blockIdx.z >> 2) {
    case 0:  in = qmap;   Wb = Wqb;  out = Qt;  break;
    case 1:  in = kvmap1; Wb = Wkvb; out = KV1; break;
    default: in = kvmap2; Wb = Wkvb; out = KV2; break;
  }
  __shared__ short wl[64 * 256];                        // 32 KB, swizzled [o'][c]
  const int ng = blockIdx.z & 3;                        // out-channel group (64)
  const int b = blockIdx.y, t = threadIdx.x;
  const int w = t >> 6, lane = t & 63, l15 = lane & 15, lg = lane >> 4;

  // cooperative W stage: 64 rows x 512B = 2048 16B-units, 8 per thread.
  {
    const short* wsrc = Wb + (size_t)(ng * 64) * CH;
    #pragma unroll
    for (int i = 0; i < 8; ++i) {
      int idx = i * 256 + t;                 // linear 16B unit
      int o = idx >> 5, slot = idx & 31;
      bf16x8 v = *(const bf16x8*)(wsrc + o * CH + slot * 8);  // coalesced
      *(bf16x8*)((char*)wl + o * 512 + ((slot * 16) ^ ((o & 7) * 16))) = v;
    }
  }

  // A-gather (direct strided dwords, lean VGPR form), overlaps the W stage
  const int pix = blockIdx.x * 64 + w * 16 + l15;       // A-row for this lane
  const float* inb = in + (size_t)b * CH * HW;
  bf16x8 a[8];                                          // c = k8*32 + lg*8 + j
  #pragma unroll
  for (int k8 = 0; k8 < 8; ++k8) {
    #pragma unroll
    for (int j = 0; j < 8; ++j)
      a[k8][j] = f2bf(inb[(size_t)(k8 * 32 + lg * 8 + j) * HW + pix]);
  }
  __syncthreads();

  const int prow = blockIdx.x * 64 + w * 16 + lg * 4;   // C-row base for store
  short* ob = out + (size_t)b * HW * CH;
  #pragma unroll
  for (int nq = 0; nq < 4; ++nq) {
    const int nt = ng * 4 + nq;
    const int o = nq * 16 + l15;                        // local W row
    f32x4 acc = (f32x4)0.f;
    #pragma unroll
    for (int k8 = 0; k8 < 8; ++k8) {
      bf16x8 bfrag = *(const bf16x8*)((char*)wl + o * 512 +
                                      (((k8 * 4 + lg) * 16) ^ ((o & 7) * 16)));
      acc = __builtin_amdgcn_mfma_f32_16x16x32_bf16(a[k8], bfrag, acc, 0, 0, 0);
    }
    #pragma unroll
    for (int r = 0; r < 4; ++r)
      ob[(size_t)(prow + r) * CH + nt * 16 + l15] = f2bf(acc[r]);
  }
}

// ---------------- MFMA local attention
// block = (8x8 pixel tile, b*4+n). 4 waves; wave w owns 16 pixels (tile rows
// 2w, 2w+1), computes only union rows [2w, 2w+7] (rest masked to P=0 anyway).
// Round-7 fix: KVT transpose-build via (4pos x 8d) register tiles ->
// 8 b128 loads + 16 ds_write_b64 per thread (was 8 loads + 64 ds_write_b16).
// posT-fastest thread mapping keeps the b64 writes ~4-way conflicted.
__global__ __launch_bounds__(256, 3) void attn_kernel(
    const short* __restrict__ Qt, const short* __restrict__ KV1,
    const short* __restrict__ KV2, float* __restrict__ out) {
  __shared__ char KVT[64 * ROWB];    // [d][pos 224] bf16, swizzled (28 KB)
  __shared__ char WT [64 * WROWB];   // [pix][pos_local 128] bf16, swizzled (16 KB)

  const int t = threadIdx.x, lane = t & 63, w = t >> 6;
  const int l15 = lane & 15, lg = lane >> 4;
  const int tile = blockIdx.x;
  const int ty = tile >> 3, tx = tile & 7;
  const int bn = blockIdx.y, b = bn >> 2, n = bn & 3;

  bf16x8 qf0, qf1;
  {
    int p = w * 16 + l15;
    int gp = (ty * 8 + (p >> 3)) * 64 + tx * 8 + (p & 7);
    const short* qb = Qt + ((size_t)b * HW + gp) * CH + n * DH + lg * 8;
    qf0 = *(const bf16x8*)(qb);
    qf1 = *(const bf16x8*)(qb + 32);
  }

  f32x4 acc2[4];
  #pragma unroll
  for (int i = 0; i < 4; ++i) acc2[i] = (f32x4)0.f;

  const int p = w * 16 + l15, px = p & 7;
  const int hi8 = l15 >> 3;              // pixel row within wave pair: py = 2w+hi8

  #pragma unroll
  for (int br = 0; br < 2; ++br) {
    const short* kv = (br ? KV2 : KV1) + (size_t)b * HW * CH + n * DH;
    if (br) __syncthreads();           // prior PV reads of KVT complete

    // ---- build KVT[d][pos]: 448 (4pos x 8d) tiles over 2 rounds ----
    #pragma unroll
    for (int it = 0; it < 2; ++it) {
      int tid = it * 256 + t;
      if (tid < 448) {
        int dc = (tid * 586) >> 15;          // tid / 56 (exact for tid < 448)
        int posT = tid - dc * 56;            // posT fastest -> spread banks
        int pos0 = posT * 4;
        int uy = pos0 >> 4, ux0 = pos0 & 15;
        int gy = ty * 8 + uy - 3;
        bool yok = (gy >= 0) && (gy < HH);
        bf16x8 v[4];
        #pragma unroll
        for (int r = 0; r < 4; ++r) {
          int ux = ux0 + r;
          int gx = tx * 8 + ux - 3;
          bool valid = yok && (ux < 14) && (gx >= 0) && (gx < WW);
          v[r] = (bf16x8)0;
          if (valid)
            v[r] = *(const bf16x8*)(kv + (size_t)(gy * WW + gx) * CH + dc * 8);
        }
        #pragma unroll
        for (int j = 0; j < 8; ++j) {
          int d = dc * 8 + j;
          short4_t pk;
          pk[0] = v[0][j]; pk[1] = v[1][j]; pk[2] = v[2][j]; pk[3] = v[3][j];
          *(short4_t*)(KVT + swz(d, d * ROWB + pos0 * 2)) = pk;
        }
      }
    }
    __syncthreads();                    // KVT ready for all waves

    // ---- S' tiles, wave-local rows mt = 2w+i, i=0..7 ----
    f32x4 sa[8];
    {
      int ux = l15;
      int gx = tx * 8 + ux - 3;
      bool xok = (ux < 14) && (gx >= 0) && (gx < WW);
      #pragma unroll
      for (int i = 0; i < 8; ++i) {
        int gy = ty * 8 + (2 * w + i) - 3;
        bool valid = xok && (gy >= 0) && (gy < HH);
        bf16x8 a0 = (bf16x8)0, a1 = (bf16x8)0;
        if (valid) {
          const short* src = kv + (size_t)(gy * WW + gx) * CH + lg * 8;
          a0 = *(const bf16x8*)(src);
          a1 = *(const bf16x8*)(src + 32);
        }
        f32x4 s = (f32x4)0.f;
        s = __builtin_amdgcn_mfma_f32_16x16x32_bf16(a0, qf0, s, 0, 0, 0);
        s = __builtin_amdgcn_mfma_f32_16x16x32_bf16(a1, qf1, s, 0, 0, 0);
        sa[i] = s;
      }
    }

    // ---- masked softmax over pos (32 lane-local + shfl over lane-groups) ----
    float m = -1e30f;
    #pragma unroll
    for (int i = 0; i < 8; ++i) {
      int dy = i - hi8;                  // (2w+i) - py
      bool yok = (dy >= 0) && (dy <= 6);
      #pragma unroll
      for (int r = 0; r < 4; ++r) {
        int dx = (lg * 4 + r) - px;
        bool in = yok && (dx >= 0) && (dx <= 6);
        float s = in ? sa[i][r] : -1e30f;
        sa[i][r] = s;
        m = fmaxf(m, s);
      }
    }
    m = fmaxf(m, __shfl_xor(m, 16, 64));
    m = fmaxf(m, __shfl_xor(m, 32, 64));
    float den = 0.f;
    #pragma unroll
    for (int i = 0; i < 8; ++i) {
      #pragma unroll
      for (int r = 0; r < 4; ++r) {
        float e = __expf(sa[i][r] - m);   // masked -> exp(-huge) = 0
        sa[i][r] = e;
        den += e;
      }
    }
    den += __shfl_xor(den, 16, 64);
    den += __shfl_xor(den, 32, 64);
    float inv = 1.f / den;

    // ---- write W^T rows, local cols (wave-private; same-wave readback) ----
    #pragma unroll
    for (int i = 0; i < 8; ++i) {
      short4_t pk;
      #pragma unroll
      for (int r = 0; r < 4; ++r) pk[r] = f2bf(sa[i][r] * inv);
      *(short4_t*)(WT + swz(p, p * WROWB + (i * 16 + lg * 4) * 2)) = pk;
    }

    // ---- PV: O[pix][d] += W^T x KV, K = 128 wave-local positions ----
    #pragma unroll 1
    for (int kp = 0; kp < 4; ++kp) {
      int lposb = (kp * 32 + lg * 8) * 2;            // WT local col byte
      int gposb = (32 * w + kp * 32 + lg * 8) * 2;   // KVT global pos byte
      bf16x8 af = *(const bf16x8*)(WT + swz(p, p * WROWB + lposb));
      #pragma unroll
      for (int ntp = 0; ntp < 4; ++ntp) {
        int brow = ntp * 16 + l15;
        bf16x8 bf = *(const bf16x8*)(KVT + swz(brow, brow * ROWB + gposb));
        acc2[ntp] = __builtin_amdgcn_mfma_f32_16x16x32_bf16(af, bf, acc2[ntp], 0, 0, 0);
      }
    }
  }

  // ---- epilogue: average branches, store f32x4 (4 consecutive pixels) ----
  int p0 = w * 16 + lg * 4;
  int gp = (ty * 8 + (p0 >> 3)) * 64 + tx * 8 + (p0 & 7);
  #pragma unroll
  for (int ntp = 0; ntp < 4; ++ntp) {
    int o = n * DH + ntp * 16 + l15;
    f32x4 v = acc2[ntp] * 0.5f;
    *(f32x4*)(out + ((size_t)b * CH + o) * HW + gp) = v;
  }
}

extern "C" void kernel_launch(void* const* d_in, const int* in_sizes, int n_in,
                              void* d_out, int out_size, void* d_ws, size_t ws_size,
                              hipStream_t stream) {
  const float* kvmap1 = (const float*)d_in[0];
  const float* qmap   = (const float*)d_in[1];
  const float* kvmap2 = (const float*)d_in[2];
  const float* Wq     = (const float*)d_in[3];
  const float* Wkv    = (const float*)d_in[4];
  float* out = (float*)d_out;

  // workspace: bf16 Qt | KV1 | KV2 (4 MB each) | Wqb | Wkvb (128 KB each)
  short* Qt   = (short*)d_ws;
  short* KV1  = Qt  + (size_t)BB * HW * CH;
  short* KV2  = KV1 + (size_t)BB * HW * CH;
  short* Wqb  = KV2 + (size_t)BB * HW * CH;
  short* Wkvb = Wqb + (size_t)CH * CH;

  dim3 wgrid(64, 2);
  wcvt_kernel<<<wgrid, 256, 0, stream>>>(Wq, Wkv, Wqb, Wkvb);

  dim3 pgrid(HW / 64, BB, 12);
  proj_mfma_kernel<<<pgrid, 256, 0, stream>>>(qmap, kvmap1, kvmap2, Wqb, Wkvb,
                                              Qt, KV1, KV2);

  dim3 agrid(64, BB * HEADS);
  attn_kernel<<<agrid, 256, 0, stream>>>(Qt, KV1, KV2, out);
}